// Round 6
// baseline (289.730 us; speedup 1.0000x reference)
//
#include <hip/hip_runtime.h>
#include <hip/hip_bf16.h>
#include <stdint.h>

// Problem constants (Gemma3n attention block)
#define S_LEN 2048
#define HIDN  2048
#define NH    8
#define NKV   2
#define HD    256

typedef _Float16 v8h  __attribute__((ext_vector_type(8)));
typedef float    v4f  __attribute__((ext_vector_type(4)));
typedef float    v16f __attribute__((ext_vector_type(16)));
typedef unsigned short u16;

struct alignas(8) US4 { u16 x, y, z, w; };

__device__ __forceinline__ u16 f2h(float f) {
  union { _Float16 h; u16 u; } t; t.h = (_Float16)f; return t.u;
}
__device__ __forceinline__ float h2f(u16 u) {
  union { _Float16 h; u16 u; } t; t.u = u; return (float)t.h;
}
__device__ __forceinline__ uint32_t pk2(float a, float b) {
  return (uint32_t)f2h(a) | ((uint32_t)f2h(b) << 16);
}

template <typename T>
__device__ __forceinline__ void gload16(const T* g, void* l) {
  __builtin_amdgcn_global_load_lds(
      (const __attribute__((address_space(1))) void*)g,
      (__attribute__((address_space(3))) void*)l, 16, 0, 0);
}

// ---------------- f32 -> f16 cast, 4 elems/thread ----------------
__global__ void cvt_h_kernel(const float* __restrict__ in, u16* __restrict__ out, int n4) {
  int i = blockIdx.x * blockDim.x + threadIdx.x;
  if (i >= n4) return;
  float4 v = reinterpret_cast<const float4*>(in)[i];
  US4 o; o.x = f2h(v.x); o.y = f2h(v.y); o.z = f2h(v.z); o.w = f2h(v.w);
  reinterpret_cast<US4*>(out)[i] = o;
}

// ---------------- f16 NT GEMM: C[m][n] = sum_k A[m][k]*B[n][k], f32 out ------
__global__ __launch_bounds__(256, 2) void gemm_h_nt(
    const u16* __restrict__ A, const u16* __restrict__ Bm,
    float* __restrict__ C, int M, int N, int K) {
  __shared__ u16 As[128 * 32];
  __shared__ u16 Bs[128 * 32];
  const int tid = threadIdx.x;
  const int w = tid >> 6, lane = tid & 63;
  const int m0 = blockIdx.x * 128, n0 = blockIdx.y * 128;
  const int wr = (w >> 1) * 64, wc = (w & 1) * 64;
  const int lr = lane & 15, lk = (lane >> 4) << 3;
  v4f acc[4][4] = {};
  const int row1 = tid >> 2, col1 = (tid & 3) << 3;
  const int t2 = tid + 256;
  const int row2 = t2 >> 2, col2 = (t2 & 3) << 3;
  for (int kt = 0; kt < K; kt += 32) {
    __syncthreads();
    gload16(A  + (size_t)(m0 + row1) * K + kt + col1, (char*)As + tid * 16);
    gload16(Bm + (size_t)(n0 + row1) * K + kt + col1, (char*)Bs + tid * 16);
    gload16(A  + (size_t)(m0 + row2) * K + kt + col2, (char*)As + t2 * 16);
    gload16(Bm + (size_t)(n0 + row2) * K + kt + col2, (char*)Bs + t2 * 16);
    __syncthreads();
    v8h af[4], bfr[4];
#pragma unroll
    for (int i = 0; i < 4; i++) af[i]  = *reinterpret_cast<const v8h*>(&As[(wr + i * 16 + lr) * 32 + lk]);
#pragma unroll
    for (int i = 0; i < 4; i++) bfr[i] = *reinterpret_cast<const v8h*>(&Bs[(wc + i * 16 + lr) * 32 + lk]);
#pragma unroll
    for (int i = 0; i < 4; i++)
#pragma unroll
      for (int jn = 0; jn < 4; jn++)
        acc[i][jn] = __builtin_amdgcn_mfma_f32_16x16x32_f16(af[i], bfr[jn], acc[i][jn], 0, 0, 0);
  }
  const int rbase = m0 + wr + ((lane >> 4) << 2);
  const int cbase = n0 + wc + lr;
#pragma unroll
  for (int i = 0; i < 4; i++)
#pragma unroll
    for (int jn = 0; jn < 4; jn++) {
      const int col = cbase + jn * 16;
#pragma unroll
      for (int j = 0; j < 4; j++)
        C[(size_t)(rbase + i * 16 + j) * N + col] = acc[i][jn][j];
    }
}

// ---------------- RMSNorm (+RoPE for Q,K) + f16 store + V transpose ----------
__global__ __launch_bounds__(256, 4) void norm_rope_kernel(
    const float* __restrict__ qkv, const float* __restrict__ cosb, const float* __restrict__ sinb,
    const float* __restrict__ qw, const float* __restrict__ kw,
    u16* __restrict__ q_t, u16* __restrict__ k_t, u16* __restrict__ v_t) {
  const int task = blockIdx.x * 4 + (threadIdx.x >> 6);
  const int lane = threadIdx.x & 63;
  const int unit = task % 12;
  const int ms = task / 12;           // b*S + s
  const int b = ms >> 11, s = ms & 2047;
  const int d0 = lane << 2;
  const int col0 = (unit < 8) ? unit * 256 : 2048 + (unit - 8) * 256;
  const float4 xv = *reinterpret_cast<const float4*>(qkv + (size_t)ms * 3072 + col0 + d0);
  float x[4] = { xv.x, xv.y, xv.z, xv.w };
  float ss = x[0]*x[0] + x[1]*x[1] + x[2]*x[2] + x[3]*x[3];
#pragma unroll
  for (int m = 1; m < 64; m <<= 1) ss += __shfl_xor(ss, m, 64);
  const float r = rsqrtf(ss * (1.0f / 256.0f) + 1e-6f);
  if (unit < 10) {
    const float4 wv = *reinterpret_cast<const float4*>(((unit < 8) ? qw : kw) + d0);
    float xn[4];
    xn[0] = x[0] * r * wv.x; xn[1] = x[1] * r * wv.y;
    xn[2] = x[2] * r * wv.z; xn[3] = x[3] * r * wv.w;
    float rot[4];
#pragma unroll
    for (int j = 0; j < 4; j++) {
      const float p = __shfl(xn[j], lane ^ 32, 64);
      rot[j] = (lane < 32) ? -p : p;   // rotate_half: (-x2, x1)
    }
    const float4 c  = *reinterpret_cast<const float4*>(cosb + (size_t)ms * 256 + d0);
    const float4 sn = *reinterpret_cast<const float4*>(sinb + (size_t)ms * 256 + d0);
    US4 o;
    o.x = f2h(xn[0] * c.x + rot[0] * sn.x);
    o.y = f2h(xn[1] * c.y + rot[1] * sn.y);
    o.z = f2h(xn[2] * c.z + rot[2] * sn.z);
    o.w = f2h(xn[3] * c.w + rot[3] * sn.w);
    if (unit < 8) {
      const size_t dst = ((size_t)(b * NH + unit) * S_LEN + s) * 256 + d0;
      *reinterpret_cast<US4*>(q_t + dst) = o;
    } else {
      const size_t dst = ((size_t)(b * NKV + (unit - 8)) * S_LEN + s) * 256 + d0;
      *reinterpret_cast<US4*>(k_t + dst) = o;
    }
  } else {
    const int kvh = unit - 10;
    u16* vt = v_t + (size_t)(b * NKV + kvh) * 256 * 2048;   // [d][s] transposed
#pragma unroll
    for (int j = 0; j < 4; j++)
      vt[(size_t)(d0 + j) * 2048 + s] = f2h(x[j] * r);
  }
}

// stage one K/V tile. K: [64 kv][32 slots x 16B], slot_phys = slot_log ^ (kv&31)
// V: [256 d][8 slots x 16B],  slot_phys = slot_log ^ ((d>>2)&7)
// gload_lds dest linear; swizzle realized by pre-permuted global source.
__device__ __forceinline__ void stage_kv(
    const u16* __restrict__ kb, const u16* __restrict__ vb, int kt,
    u16* Kbuf, u16* Vbuf, int tid) {
#pragma unroll
  for (int it = 0; it < 4; it++) {
    const int i1 = tid + it * 512;
    const int kv = i1 >> 5, sp = i1 & 31;
    const int sl = sp ^ (kv & 31);
    gload16(kb + (size_t)(kt * 64 + kv) * 256 + sl * 8, (char*)Kbuf + i1 * 16);
    const int d = i1 >> 3, sp2 = i1 & 7;
    const int sl2 = sp2 ^ ((d >> 2) & 7);
    gload16(vb + (size_t)d * 2048 + kt * 64 + sl2 * 8, (char*)Vbuf + i1 * 16);
  }
}

// ---------------- causal flash attention, fp16 32x32 MFMA, split-K=2 ---------
// grid (32 = 16 qt x 2 z, heavy-first; 16 bh); 512 thr = 8 waves =
// 4 q-groups(32 rows) x 2 d-halves. QB=128, KB=64. Swapped QK^T (mfma(K,Q)):
// P stays lane-local (col=lane&31 = q-row); softmax in-register; P->B-frag via
// 16 packed shfl_xor(32). PV: O^T = mfma(V^T, P^T), d-half per wave.
// LDS 128KB dbuf; counted vmcnt(8); 2 raw barriers/tile.
__global__ __launch_bounds__(512, 2) void attn_kernel(
    const u16* __restrict__ q_t, const u16* __restrict__ k_t,
    const u16* __restrict__ v_t, u16* __restrict__ oP, float2* __restrict__ ml) {
  const int qt = 15 - (blockIdx.x >> 1);   // heavy-first
  const int z  = blockIdx.x & 1;
  const int bh = blockIdx.y;
  const int b = bh >> 3, h = bh & 7, hk = h >> 2;
  const int tid = threadIdx.x;
  const int w = tid >> 6, lane = tid & 63;
  const int g = w >> 1, hf = w & 1;
  const int l31 = lane & 31, hi = lane >> 5;

  __shared__ u16 Kb[2][16384];   // 2 x 32KB [kv][slot16B] swizzled
  __shared__ u16 Vb[2][16384];   // 2 x 32KB [d][slot16B] swizzled

  // Q B-fragments: q = qt*128 + g*32 + l31, d = dstep*16 + hi*8 + j  (64 VGPR)
  const u16* qb = q_t + ((size_t)(b * NH + h) * S_LEN + qt * 128 + g * 32 + l31) * 256;
  v8h qf[16];
#pragma unroll
  for (int f = 0; f < 16; f++)
    qf[f] = *reinterpret_cast<const v8h*>(qb + f * 16 + hi * 8);

  v16f o[4] = {};        // O^T[d = hf*128 + dblk*32 + row(reg)][q = l31]
  float mr = -1e30f, lsum = 0.f;

  const u16* kb = k_t + (size_t)(b * NKV + hk) * S_LEN * 256;
  const u16* vb = v_t + (size_t)(b * NKV + hk) * 256 * S_LEN;

  const int kt0 = z * (qt + 1);
  const int kt1 = kt0 + (qt + 1);

  stage_kv(kb, vb, kt0, Kb[0], Vb[0], tid);

  for (int kt = kt0; kt < kt1; kt++) {
    const int cb = (kt - kt0) & 1;
    if (kt + 1 < kt1) {
      stage_kv(kb, vb, kt + 1, Kb[cb ^ 1], Vb[cb ^ 1], tid);
      asm volatile("s_waitcnt vmcnt(8)" ::: "memory");
    } else {
      asm volatile("s_waitcnt vmcnt(0)" ::: "memory");
    }
    __builtin_amdgcn_s_barrier();
    __builtin_amdgcn_sched_barrier(0);

    // QK^T swapped: S^T[kv][q], kv = nkv*32 + (r&3)+8*(r>>2)+4*hi, q = l31
    v16f s0 = {}, s1 = {};
#pragma unroll
    for (int ds = 0; ds < 16; ds++) {
      const int sp = (ds * 2 + hi) ^ l31;
      const v8h kf0 = *reinterpret_cast<const v8h*>(&Kb[cb][l31 * 256 + sp * 8]);
      const v8h kf1 = *reinterpret_cast<const v8h*>(&Kb[cb][(32 + l31) * 256 + sp * 8]);
      s0 = __builtin_amdgcn_mfma_f32_32x32x16_f16(kf0, qf[ds], s0, 0, 0, 0);
      s1 = __builtin_amdgcn_mfma_f32_32x32x16_f16(kf1, qf[ds], s1, 0, 0, 0);
    }
    if (kt >= 2 * qt) {   // diagonal tile: causal mask
      const int qg = qt * 128 + g * 32 + l31;
#pragma unroll
      for (int r = 0; r < 16; r++) {
        const int kvr = kt * 64 + (r & 3) + 8 * (r >> 2) + 4 * hi;
        if (kvr > qg) s0[r] = -1e30f;
        if (kvr + 32 > qg) s1[r] = -1e30f;
      }
    }
    // in-register online softmax (lane owns one q-row's 32 kv; +partner via shfl)
    float pm = s0[0];
#pragma unroll
    for (int r = 1; r < 16; r++) pm = fmaxf(pm, s0[r]);
#pragma unroll
    for (int r = 0; r < 16; r++) pm = fmaxf(pm, s1[r]);
    pm = fmaxf(pm, __shfl_xor(pm, 32, 64));
    if (!__all(pm - mr <= 8.0f)) {       // T13 defer-max
      const float mn = fmaxf(mr, pm);
      const float sc = __expf(mr - mn);
      mr = mn;
      lsum *= sc;
#pragma unroll
      for (int dblk = 0; dblk < 4; dblk++)
#pragma unroll
        for (int r = 0; r < 16; r++) o[dblk][r] *= sc;
    }
    float rs = 0.f;
#pragma unroll
    for (int r = 0; r < 16; r++) { s0[r] = __expf(s0[r] - mr); rs += s0[r]; }
#pragma unroll
    for (int r = 0; r < 16; r++) { s1[r] = __expf(s1[r] - mr); rs += s1[r]; }
    rs += __shfl_xor(rs, 32, 64);
    lsum += rs;
    // pack P^T pairs and exchange lane-halves (kv +-4 lives in lane^32)
    uint32_t pka[2][8], pkx[2][8];
#pragma unroll
    for (int u = 0; u < 8; u++) {
      const int r = (u & 1) * 2 + (u >> 1) * 4;
      pka[0][u] = pk2(s0[r], s0[r + 1]);
      pka[1][u] = pk2(s1[r], s1[r + 1]);
    }
#pragma unroll
    for (int n = 0; n < 2; n++)
#pragma unroll
      for (int u = 0; u < 8; u++)
        pkx[n][u] = (uint32_t)__shfl_xor((int)pka[n][u], 32, 64);
    // B-fragments for PV: P^T[kv = s*16 + hi*8 + j][q = l31]
    v8h bfr[4];
#pragma unroll
    for (int s = 0; s < 4; s++) {
      const int n = s >> 1, base = (s & 1) * 4;
      union { uint32_t u[4]; v8h h; } t;
      if (hi == 0) {
        t.u[0] = pka[n][base];     t.u[1] = pka[n][base + 1];
        t.u[2] = pkx[n][base];     t.u[3] = pkx[n][base + 1];
      } else {
        t.u[0] = pkx[n][base + 2]; t.u[1] = pkx[n][base + 3];
        t.u[2] = pka[n][base + 2]; t.u[3] = pka[n][base + 3];
      }
      bfr[s] = t.h;
    }
    // PV: O^T[d][q] += V^T[d][kv] * P^T[kv][q], d-half hf
#pragma unroll
    for (int dblk = 0; dblk < 4; dblk++) {
      const int d = hf * 128 + dblk * 32 + l31;
#pragma unroll
      for (int s = 0; s < 4; s++) {
        const int sp = (s * 2 + hi) ^ ((d >> 2) & 7);
        const v8h vf = *reinterpret_cast<const v8h*>(&Vb[cb][d * 64 + sp * 8]);
        o[dblk] = __builtin_amdgcn_mfma_f32_32x32x16_f16(vf, bfr[s], o[dblk], 0, 0, 0);
      }
    }
    __builtin_amdgcn_s_barrier();
    __builtin_amdgcn_sched_barrier(0);
  }

  // write unnormalized partial (f16) + (m, l)
  const size_t rowi = (((size_t)(z * 16 + bh)) * 16 + qt) * 128 + g * 32 + l31;
  u16* ob = oP + rowi * 256;
#pragma unroll
  for (int dblk = 0; dblk < 4; dblk++)
#pragma unroll
    for (int rr = 0; rr < 4; rr++) {
      const int dbase = hf * 128 + dblk * 32 + rr * 8 + hi * 4;
      uint2 pw;
      pw.x = pk2(o[dblk][rr * 4 + 0], o[dblk][rr * 4 + 1]);
      pw.y = pk2(o[dblk][rr * 4 + 2], o[dblk][rr * 4 + 3]);
      *reinterpret_cast<uint2*>(ob + dbase) = pw;
    }
  if (hf == 0 && lane < 32)
    ml[rowi] = make_float2(mr, lsum);
}

// ---------------- split-K combine: merge 2 partials -> aout f16 --------------
__global__ __launch_bounds__(256, 8) void combine_kernel(
    const u16* __restrict__ oP, const float2* __restrict__ ml,
    u16* __restrict__ aout) {
  const int wid = threadIdx.x >> 6, lane = threadIdx.x & 63;
  const int R = blockIdx.x * 4 + wid;          // 0..32767 = (bh, qt, row)
  const int bh = R >> 11, rem = R & 2047, qt = rem >> 7, row = rem & 127;
  const int b = bh >> 3, h = bh & 7;
  const size_t i0 = (((size_t)bh)      * 16 + qt) * 128 + row;
  const size_t i1 = (((size_t)(16+bh)) * 16 + qt) * 128 + row;
  const float2 m0 = ml[i0], m1 = ml[i1];
  const float ms = fmaxf(m0.x, m1.x);
  const float f0 = __expf(m0.x - ms), f1 = __expf(m1.x - ms);
  const float inv = 1.0f / (m0.y * f0 + m1.y * f1);
  const US4 a = reinterpret_cast<const US4*>(oP + i0 * 256)[lane];
  const US4 c = reinterpret_cast<const US4*>(oP + i1 * 256)[lane];
  US4 o;
  o.x = f2h((h2f(a.x) * f0 + h2f(c.x) * f1) * inv);
  o.y = f2h((h2f(a.y) * f0 + h2f(c.y) * f1) * inv);
  o.z = f2h((h2f(a.z) * f0 + h2f(c.z) * f1) * inv);
  o.w = f2h((h2f(a.w) * f0 + h2f(c.w) * f1) * inv);
  u16* dst = aout + ((size_t)(b * 2048 + qt * 128 + row)) * 2048 + h * 256 + lane * 4;
  *reinterpret_cast<US4*>(dst) = o;
}

extern "C" void kernel_launch(void* const* d_in, const int* in_sizes, int n_in,
                              void* d_out, int out_size, void* d_ws, size_t ws_size,
                              hipStream_t stream) {
  const float* hs   = (const float*)d_in[0];
  const float* cosb = (const float*)d_in[1];
  const float* sinb = (const float*)d_in[2];
  // d_in[3] attention_mask: exactly causal -> applied analytically in attn_kernel
  const float* Wq = (const float*)d_in[4];
  const float* Wk = (const float*)d_in[5];
  const float* Wv = (const float*)d_in[6];
  const float* Wo = (const float*)d_in[7];
  const float* qw = (const float*)d_in[8];
  const float* kw = (const float*)d_in[9];
  float* out = (float*)d_out;

  char* ws = (char*)d_ws;
  u16* hs_f = (u16*)(ws + 0);            // 16.78MB f16 (4096x2048)
  u16* w_f  = (u16*)(ws + 16777216);     // 12.58MB f16 (Wq|Wk|Wv rows, 3072x2048)
  u16* wo_f = (u16*)(ws + 29360128);     //  8.39MB f16 (2048x2048)
  float* qkv = (float*)(ws + 37748736);  // 50.33MB f32 (ends 88,080,384)
  u16* q_t  = (u16*)(ws + 88080384);     // 16.78MB f16 (B,NH,S,HD)
  u16* k_t  = (u16*)(ws + 104857600);    //  4.19MB f16 (B,NKV,S,HD)
  u16* v_t  = (u16*)(ws + 109051904);    //  4.19MB f16 (B,NKV,HD,S)  ends 113.2MB
  // late-phase aliases (producers of aliased regions complete first)
  u16* oP   = (u16*)(ws + 37748736);     // 33.55MB f16 partials (aliases qkv)
  float2* mlp = (float2*)(ws + 71303168);// 0.52MB (aliases qkv tail)
  u16* aout = (u16*)(ws + 0);            // 16.78MB f16 (aliases hs_f, gemm1 done)

  cvt_h_kernel<<<8192, 256, 0, stream>>>(hs, hs_f, 2097152);
  cvt_h_kernel<<<4096, 256, 0, stream>>>(Wq, w_f,           1048576);
  cvt_h_kernel<<<1024, 256, 0, stream>>>(Wk, w_f + 4194304, 262144);
  cvt_h_kernel<<<1024, 256, 0, stream>>>(Wv, w_f + 5242880, 262144);
  cvt_h_kernel<<<4096, 256, 0, stream>>>(Wo, wo_f,          1048576);

  gemm_h_nt<<<dim3(32, 24), 256, 0, stream>>>(hs_f, w_f, qkv, 4096, 3072, 2048);
  norm_rope_kernel<<<12288, 256, 0, stream>>>(qkv, cosb, sinb, qw, kw, q_t, k_t, v_t);
  attn_kernel<<<dim3(32, 16), 512, 0, stream>>>(q_t, k_t, v_t, oP, mlp);
  combine_kernel<<<8192, 256, 0, stream>>>(oP, mlp, aout);
  gemm_h_nt<<<dim3(32, 16), 256, 0, stream>>>(aout, wo_f, out, 4096, 2048, 2048);
}

// Round 7
// 250.015 us; speedup vs baseline: 1.1588x; 1.1588x over previous
//
#include <hip/hip_runtime.h>
#include <hip/hip_bf16.h>
#include <stdint.h>

// Problem constants (Gemma3n attention block)
#define S_LEN 2048
#define HIDN  2048
#define NH    8
#define NKV   2
#define HD    256

typedef _Float16 v8h  __attribute__((ext_vector_type(8)));
typedef float    v4f  __attribute__((ext_vector_type(4)));
typedef float    v16f __attribute__((ext_vector_type(16)));
typedef unsigned short u16;

struct alignas(8) US4 { u16 x, y, z, w; };

__device__ __forceinline__ u16 f2h(float f) {
  union { _Float16 h; u16 u; } t; t.h = (_Float16)f; return t.u;
}
__device__ __forceinline__ float h2f(u16 u) {
  union { _Float16 h; u16 u; } t; t.u = u; return (float)t.h;
}
__device__ __forceinline__ uint32_t pk2(float a, float b) {
  return (uint32_t)f2h(a) | ((uint32_t)f2h(b) << 16);
}

template <typename T>
__device__ __forceinline__ void gload16(const T* g, void* l) {
  __builtin_amdgcn_global_load_lds(
      (const __attribute__((address_space(1))) void*)g,
      (__attribute__((address_space(3))) void*)l, 16, 0, 0);
}

// ---------------- f32 -> f16 cast, 4 elems/thread ----------------
__global__ void cvt_h_kernel(const float* __restrict__ in, u16* __restrict__ out, int n4) {
  int i = blockIdx.x * blockDim.x + threadIdx.x;
  if (i >= n4) return;
  float4 v = reinterpret_cast<const float4*>(in)[i];
  US4 o; o.x = f2h(v.x); o.y = f2h(v.y); o.z = f2h(v.z); o.w = f2h(v.w);
  reinterpret_cast<US4*>(out)[i] = o;
}

// ---------------- f16 NT GEMM: C[m][n] = sum_k A[m][k]*B[n][k], f32 out ------
__global__ __launch_bounds__(256, 2) void gemm_h_nt(
    const u16* __restrict__ A, const u16* __restrict__ Bm,
    float* __restrict__ C, int M, int N, int K) {
  __shared__ u16 As[128 * 32];
  __shared__ u16 Bs[128 * 32];
  const int tid = threadIdx.x;
  const int w = tid >> 6, lane = tid & 63;
  const int m0 = blockIdx.x * 128, n0 = blockIdx.y * 128;
  const int wr = (w >> 1) * 64, wc = (w & 1) * 64;
  const int lr = lane & 15, lk = (lane >> 4) << 3;
  v4f acc[4][4] = {};
  const int row1 = tid >> 2, col1 = (tid & 3) << 3;
  const int t2 = tid + 256;
  const int row2 = t2 >> 2, col2 = (t2 & 3) << 3;
  for (int kt = 0; kt < K; kt += 32) {
    __syncthreads();
    gload16(A  + (size_t)(m0 + row1) * K + kt + col1, (char*)As + tid * 16);
    gload16(Bm + (size_t)(n0 + row1) * K + kt + col1, (char*)Bs + tid * 16);
    gload16(A  + (size_t)(m0 + row2) * K + kt + col2, (char*)As + t2 * 16);
    gload16(Bm + (size_t)(n0 + row2) * K + kt + col2, (char*)Bs + t2 * 16);
    __syncthreads();
    v8h af[4], bfr[4];
#pragma unroll
    for (int i = 0; i < 4; i++) af[i]  = *reinterpret_cast<const v8h*>(&As[(wr + i * 16 + lr) * 32 + lk]);
#pragma unroll
    for (int i = 0; i < 4; i++) bfr[i] = *reinterpret_cast<const v8h*>(&Bs[(wc + i * 16 + lr) * 32 + lk]);
#pragma unroll
    for (int i = 0; i < 4; i++)
#pragma unroll
      for (int jn = 0; jn < 4; jn++)
        acc[i][jn] = __builtin_amdgcn_mfma_f32_16x16x32_f16(af[i], bfr[jn], acc[i][jn], 0, 0, 0);
  }
  const int rbase = m0 + wr + ((lane >> 4) << 2);
  const int cbase = n0 + wc + lr;
#pragma unroll
  for (int i = 0; i < 4; i++)
#pragma unroll
    for (int jn = 0; jn < 4; jn++) {
      const int col = cbase + jn * 16;
#pragma unroll
      for (int j = 0; j < 4; j++)
        C[(size_t)(rbase + i * 16 + j) * N + col] = acc[i][jn][j];
    }
}

// ---------------- RMSNorm (+RoPE for Q,K) + f16 store + V transpose ----------
__global__ __launch_bounds__(256, 4) void norm_rope_kernel(
    const float* __restrict__ qkv, const float* __restrict__ cosb, const float* __restrict__ sinb,
    const float* __restrict__ qw, const float* __restrict__ kw,
    u16* __restrict__ q_t, u16* __restrict__ k_t, u16* __restrict__ v_t) {
  const int task = blockIdx.x * 4 + (threadIdx.x >> 6);
  const int lane = threadIdx.x & 63;
  const int unit = task % 12;
  const int ms = task / 12;           // b*S + s
  const int b = ms >> 11, s = ms & 2047;
  const int d0 = lane << 2;
  const int col0 = (unit < 8) ? unit * 256 : 2048 + (unit - 8) * 256;
  const float4 xv = *reinterpret_cast<const float4*>(qkv + (size_t)ms * 3072 + col0 + d0);
  float x[4] = { xv.x, xv.y, xv.z, xv.w };
  float ss = x[0]*x[0] + x[1]*x[1] + x[2]*x[2] + x[3]*x[3];
#pragma unroll
  for (int m = 1; m < 64; m <<= 1) ss += __shfl_xor(ss, m, 64);
  const float r = rsqrtf(ss * (1.0f / 256.0f) + 1e-6f);
  if (unit < 10) {
    const float4 wv = *reinterpret_cast<const float4*>(((unit < 8) ? qw : kw) + d0);
    float xn[4];
    xn[0] = x[0] * r * wv.x; xn[1] = x[1] * r * wv.y;
    xn[2] = x[2] * r * wv.z; xn[3] = x[3] * r * wv.w;
    float rot[4];
#pragma unroll
    for (int j = 0; j < 4; j++) {
      const float p = __shfl(xn[j], lane ^ 32, 64);
      rot[j] = (lane < 32) ? -p : p;   // rotate_half: (-x2, x1)
    }
    const float4 c  = *reinterpret_cast<const float4*>(cosb + (size_t)ms * 256 + d0);
    const float4 sn = *reinterpret_cast<const float4*>(sinb + (size_t)ms * 256 + d0);
    US4 o;
    o.x = f2h(xn[0] * c.x + rot[0] * sn.x);
    o.y = f2h(xn[1] * c.y + rot[1] * sn.y);
    o.z = f2h(xn[2] * c.z + rot[2] * sn.z);
    o.w = f2h(xn[3] * c.w + rot[3] * sn.w);
    if (unit < 8) {
      const size_t dst = ((size_t)(b * NH + unit) * S_LEN + s) * 256 + d0;
      *reinterpret_cast<US4*>(q_t + dst) = o;
    } else {
      const size_t dst = ((size_t)(b * NKV + (unit - 8)) * S_LEN + s) * 256 + d0;
      *reinterpret_cast<US4*>(k_t + dst) = o;
    }
  } else {
    const int kvh = unit - 10;
    u16* vt = v_t + (size_t)(b * NKV + kvh) * 256 * 2048;   // [d][s] transposed
#pragma unroll
    for (int j = 0; j < 4; j++)
      vt[(size_t)(d0 + j) * 2048 + s] = f2h(x[j] * r);
  }
}

// stage one K/V tile. K: [64 kv][32 slots x 16B], slot_phys = slot_log ^ (kv&31)
// V: [256 d][8 slots x 16B],  slot_phys = slot_log ^ ((d>>2)&7)
// gload_lds dest linear; swizzle realized by pre-permuted global source.
__device__ __forceinline__ void stage_kv(
    const u16* __restrict__ kb, const u16* __restrict__ vb, int kt,
    u16* Kbuf, u16* Vbuf, int tid) {
#pragma unroll
  for (int it = 0; it < 4; it++) {
    const int i1 = tid + it * 512;
    const int kv = i1 >> 5, sp = i1 & 31;
    const int sl = sp ^ (kv & 31);
    gload16(kb + (size_t)(kt * 64 + kv) * 256 + sl * 8, (char*)Kbuf + i1 * 16);
    const int d = i1 >> 3, sp2 = i1 & 7;
    const int sl2 = sp2 ^ ((d >> 2) & 7);
    gload16(vb + (size_t)d * 2048 + kt * 64 + sl2 * 8, (char*)Vbuf + i1 * 16);
  }
}

// ---------------- causal flash attention, fp16 32x32 MFMA --------------------
// PERFECT BALANCE: grid (16 qt, 16 bh) = 256 blocks = 1/CU, all resident.
// Each block runs item A=(qtA, z=0: tiles 0..qtA) then item B=(qtB=15-qtA,
// z=1: tiles qtB+1..2qtB+1): (qtA+1)+(16-qtA) = 17 tiles for EVERY block.
// 512 thr = 8 waves = 4 q-groups(32 rows) x 2 d-halves. QB=128, KB=64.
// Swapped QK^T (mfma(K,Q)): P lane-local, in-register softmax, P->B-frag via
// packed shfl_xor(32). Dbuf LDS 128KB, counted vmcnt(8), setprio on MFMA.
__global__ __launch_bounds__(512, 2) void attn_kernel(
    const u16* __restrict__ q_t, const u16* __restrict__ k_t,
    const u16* __restrict__ v_t, u16* __restrict__ oP, float2* __restrict__ ml) {
  const int qtA = blockIdx.x;
  const int qtB = 15 - qtA;
  const int bh = blockIdx.y;
  const int b = bh >> 3, h = bh & 7, hk = h >> 2;
  const int tid = threadIdx.x;
  const int w = tid >> 6, lane = tid & 63;
  const int g = w >> 1, hf = w & 1;
  const int l31 = lane & 31, hi = lane >> 5;

  __shared__ u16 Kb[2][16384];   // 2 x 32KB [kv][slot16B] swizzled
  __shared__ u16 Vb[2][16384];   // 2 x 32KB [d][slot16B] swizzled

  const u16* qhead = q_t + (size_t)(b * NH + h) * S_LEN * 256;
  const u16* kb = k_t + (size_t)(b * NKV + hk) * S_LEN * 256;
  const u16* vb = v_t + (size_t)(b * NKV + hk) * 256 * S_LEN;

  // Q B-fragments for item A: q = qtA*128 + g*32 + l31, d = f*16 + hi*8 + j
  const u16* qbA = qhead + (size_t)(qtA * 128 + g * 32 + l31) * 256;
  v8h qf[16];
#pragma unroll
  for (int f = 0; f < 16; f++)
    qf[f] = *reinterpret_cast<const v8h*>(qbA + f * 16 + hi * 8);

  v16f o[4] = {};        // O^T[d = hf*128 + dblk*32 + row(reg)][q = l31]
  float mr = -1e30f, lsum = 0.f;
  int qt_cur = qtA;

  const int nA = qtA + 1;          // item A tile count; total is always 17

  stage_kv(kb, vb, 0, Kb[0], Vb[0], tid);

  for (int s = 0; s < 17; s++) {
    const int cb = s & 1;
    const int kt = (s < nA) ? s : (qtB + 1 + s - nA);
    if (s + 1 < 17) {
      const int s1 = s + 1;
      const int ktn = (s1 < nA) ? s1 : (qtB + 1 + s1 - nA);
      stage_kv(kb, vb, ktn, Kb[cb ^ 1], Vb[cb ^ 1], tid);
      asm volatile("s_waitcnt vmcnt(8)" ::: "memory");
    } else {
      asm volatile("s_waitcnt vmcnt(0)" ::: "memory");
    }
    __builtin_amdgcn_s_barrier();
    __builtin_amdgcn_sched_barrier(0);

    if (s == nA) {
      // ---- item boundary: flush A's partial, reset state, load B's Q ----
      const size_t rowi = (((size_t)bh) * 16 + qtA) * 128 + g * 32 + l31;  // z=0
      u16* ob = oP + rowi * 256;
#pragma unroll
      for (int dblk = 0; dblk < 4; dblk++)
#pragma unroll
        for (int rr = 0; rr < 4; rr++) {
          const int dbase = hf * 128 + dblk * 32 + rr * 8 + hi * 4;
          uint2 pw;
          pw.x = pk2(o[dblk][rr * 4 + 0], o[dblk][rr * 4 + 1]);
          pw.y = pk2(o[dblk][rr * 4 + 2], o[dblk][rr * 4 + 3]);
          *reinterpret_cast<uint2*>(ob + dbase) = pw;
        }
      if (hf == 0 && lane < 32)
        ml[rowi] = make_float2(mr, lsum);
      const u16* qbB = qhead + (size_t)(qtB * 128 + g * 32 + l31) * 256;
#pragma unroll
      for (int f = 0; f < 16; f++)
        qf[f] = *reinterpret_cast<const v8h*>(qbB + f * 16 + hi * 8);
#pragma unroll
      for (int dblk = 0; dblk < 4; dblk++) o[dblk] = v16f{};
      mr = -1e30f; lsum = 0.f;
      qt_cur = qtB;
    }

    // QK^T swapped: S^T[kv][q], kv = nkv*32 + (r&3)+8*(r>>2)+4*hi, q = l31
    v16f s0 = {}, s1 = {};
    __builtin_amdgcn_s_setprio(1);
#pragma unroll
    for (int ds = 0; ds < 16; ds++) {
      const int sp = (ds * 2 + hi) ^ l31;
      const v8h kf0 = *reinterpret_cast<const v8h*>(&Kb[cb][l31 * 256 + sp * 8]);
      const v8h kf1 = *reinterpret_cast<const v8h*>(&Kb[cb][(32 + l31) * 256 + sp * 8]);
      s0 = __builtin_amdgcn_mfma_f32_32x32x16_f16(kf0, qf[ds], s0, 0, 0, 0);
      s1 = __builtin_amdgcn_mfma_f32_32x32x16_f16(kf1, qf[ds], s1, 0, 0, 0);
    }
    __builtin_amdgcn_s_setprio(0);
    if (kt >= 2 * qt_cur) {   // diagonal tile: causal mask
      const int qg = qt_cur * 128 + g * 32 + l31;
#pragma unroll
      for (int r = 0; r < 16; r++) {
        const int kvr = kt * 64 + (r & 3) + 8 * (r >> 2) + 4 * hi;
        if (kvr > qg) s0[r] = -1e30f;
        if (kvr + 32 > qg) s1[r] = -1e30f;
      }
    }
    // in-register online softmax (lane owns one q-row's 32 kv; partner via shfl)
    float pm = s0[0];
#pragma unroll
    for (int r = 1; r < 16; r++) pm = fmaxf(pm, s0[r]);
#pragma unroll
    for (int r = 0; r < 16; r++) pm = fmaxf(pm, s1[r]);
    pm = fmaxf(pm, __shfl_xor(pm, 32, 64));
    if (!__all(pm - mr <= 8.0f)) {       // T13 defer-max
      const float mn = fmaxf(mr, pm);
      const float sc = __expf(mr - mn);
      mr = mn;
      lsum *= sc;
#pragma unroll
      for (int dblk = 0; dblk < 4; dblk++)
#pragma unroll
        for (int r = 0; r < 16; r++) o[dblk][r] *= sc;
    }
    float rs = 0.f;
#pragma unroll
    for (int r = 0; r < 16; r++) { s0[r] = __expf(s0[r] - mr); rs += s0[r]; }
#pragma unroll
    for (int r = 0; r < 16; r++) { s1[r] = __expf(s1[r] - mr); rs += s1[r]; }
    rs += __shfl_xor(rs, 32, 64);
    lsum += rs;
    // pack P^T pairs and exchange lane-halves (kv +-4 lives in lane^32)
    uint32_t pka[2][8], pkx[2][8];
#pragma unroll
    for (int u = 0; u < 8; u++) {
      const int r = (u & 1) * 2 + (u >> 1) * 4;
      pka[0][u] = pk2(s0[r], s0[r + 1]);
      pka[1][u] = pk2(s1[r], s1[r + 1]);
    }
#pragma unroll
    for (int n = 0; n < 2; n++)
#pragma unroll
      for (int u = 0; u < 8; u++)
        pkx[n][u] = (uint32_t)__shfl_xor((int)pka[n][u], 32, 64);
    // B-fragments for PV: P^T[kv = sblk*16 + hi*8 + j][q = l31]
    v8h bfr[4];
#pragma unroll
    for (int sblk = 0; sblk < 4; sblk++) {
      const int n = sblk >> 1, base = (sblk & 1) * 4;
      union { uint32_t u[4]; v8h h; } t;
      if (hi == 0) {
        t.u[0] = pka[n][base];     t.u[1] = pka[n][base + 1];
        t.u[2] = pkx[n][base];     t.u[3] = pkx[n][base + 1];
      } else {
        t.u[0] = pkx[n][base + 2]; t.u[1] = pkx[n][base + 3];
        t.u[2] = pka[n][base + 2]; t.u[3] = pka[n][base + 3];
      }
      bfr[sblk] = t.h;
    }
    // PV: O^T[d][q] += V^T[d][kv] * P^T[kv][q], d-half hf
    __builtin_amdgcn_s_setprio(1);
#pragma unroll
    for (int dblk = 0; dblk < 4; dblk++) {
      const int d = hf * 128 + dblk * 32 + l31;
#pragma unroll
      for (int sblk = 0; sblk < 4; sblk++) {
        const int sp = (sblk * 2 + hi) ^ ((d >> 2) & 7);
        const v8h vf = *reinterpret_cast<const v8h*>(&Vb[cb][d * 64 + sp * 8]);
        o[dblk] = __builtin_amdgcn_mfma_f32_32x32x16_f16(vf, bfr[sblk], o[dblk], 0, 0, 0);
      }
    }
    __builtin_amdgcn_s_setprio(0);
    __builtin_amdgcn_s_barrier();
    __builtin_amdgcn_sched_barrier(0);
  }

  // write item B's unnormalized partial (z=1) + (m, l)
  const size_t rowi = (((size_t)(16 + bh)) * 16 + qtB) * 128 + g * 32 + l31;
  u16* ob = oP + rowi * 256;
#pragma unroll
  for (int dblk = 0; dblk < 4; dblk++)
#pragma unroll
    for (int rr = 0; rr < 4; rr++) {
      const int dbase = hf * 128 + dblk * 32 + rr * 8 + hi * 4;
      uint2 pw;
      pw.x = pk2(o[dblk][rr * 4 + 0], o[dblk][rr * 4 + 1]);
      pw.y = pk2(o[dblk][rr * 4 + 2], o[dblk][rr * 4 + 3]);
      *reinterpret_cast<uint2*>(ob + dbase) = pw;
    }
  if (hf == 0 && lane < 32)
    ml[rowi] = make_float2(mr, lsum);
}

// ---------------- split-K combine: merge 2 partials -> aout f16 --------------
__global__ __launch_bounds__(256, 8) void combine_kernel(
    const u16* __restrict__ oP, const float2* __restrict__ ml,
    u16* __restrict__ aout) {
  const int wid = threadIdx.x >> 6, lane = threadIdx.x & 63;
  const int R = blockIdx.x * 4 + wid;          // 0..32767 = (bh, qt, row)
  const int bh = R >> 11, rem = R & 2047, qt = rem >> 7, row = rem & 127;
  const int b = bh >> 3, h = bh & 7;
  const size_t i0 = (((size_t)bh)      * 16 + qt) * 128 + row;
  const size_t i1 = (((size_t)(16+bh)) * 16 + qt) * 128 + row;
  const float2 m0 = ml[i0], m1 = ml[i1];
  const float ms = fmaxf(m0.x, m1.x);
  const float f0 = __expf(m0.x - ms), f1 = __expf(m1.x - ms);
  const float inv = 1.0f / (m0.y * f0 + m1.y * f1);
  const US4 a = reinterpret_cast<const US4*>(oP + i0 * 256)[lane];
  const US4 c = reinterpret_cast<const US4*>(oP + i1 * 256)[lane];
  US4 o;
  o.x = f2h((h2f(a.x) * f0 + h2f(c.x) * f1) * inv);
  o.y = f2h((h2f(a.y) * f0 + h2f(c.y) * f1) * inv);
  o.z = f2h((h2f(a.z) * f0 + h2f(c.z) * f1) * inv);
  o.w = f2h((h2f(a.w) * f0 + h2f(c.w) * f1) * inv);
  u16* dst = aout + ((size_t)(b * 2048 + qt * 128 + row)) * 2048 + h * 256 + lane * 4;
  *reinterpret_cast<US4*>(dst) = o;
}

extern "C" void kernel_launch(void* const* d_in, const int* in_sizes, int n_in,
                              void* d_out, int out_size, void* d_ws, size_t ws_size,
                              hipStream_t stream) {
  const float* hs   = (const float*)d_in[0];
  const float* cosb = (const float*)d_in[1];
  const float* sinb = (const float*)d_in[2];
  // d_in[3] attention_mask: exactly causal -> applied analytically in attn_kernel
  const float* Wq = (const float*)d_in[4];
  const float* Wk = (const float*)d_in[5];
  const float* Wv = (const float*)d_in[6];
  const float* Wo = (const float*)d_in[7];
  const float* qw = (const float*)d_in[8];
  const float* kw = (const float*)d_in[9];
  float* out = (float*)d_out;

  char* ws = (char*)d_ws;
  u16* hs_f = (u16*)(ws + 0);            // 16.78MB f16 (4096x2048)
  u16* w_f  = (u16*)(ws + 16777216);     // 12.58MB f16 (Wq|Wk|Wv rows, 3072x2048)
  u16* wo_f = (u16*)(ws + 29360128);     //  8.39MB f16 (2048x2048)
  float* qkv = (float*)(ws + 37748736);  // 50.33MB f32 (ends 88,080,384)
  u16* q_t  = (u16*)(ws + 88080384);     // 16.78MB f16 (B,NH,S,HD)
  u16* k_t  = (u16*)(ws + 104857600);    //  4.19MB f16 (B,NKV,S,HD)
  u16* v_t  = (u16*)(ws + 109051904);    //  4.19MB f16 (B,NKV,HD,S)  ends 113.2MB
  // late-phase aliases (producers of aliased regions complete first)
  u16* oP   = (u16*)(ws + 37748736);     // 33.55MB f16 partials (aliases qkv)
  float2* mlp = (float2*)(ws + 71303168);// 0.52MB (aliases qkv tail)
  u16* aout = (u16*)(ws + 0);            // 16.78MB f16 (aliases hs_f, gemm1 done)

  cvt_h_kernel<<<8192, 256, 0, stream>>>(hs, hs_f, 2097152);
  cvt_h_kernel<<<4096, 256, 0, stream>>>(Wq, w_f,           1048576);
  cvt_h_kernel<<<1024, 256, 0, stream>>>(Wk, w_f + 4194304, 262144);
  cvt_h_kernel<<<1024, 256, 0, stream>>>(Wv, w_f + 5242880, 262144);
  cvt_h_kernel<<<4096, 256, 0, stream>>>(Wo, wo_f,          1048576);

  gemm_h_nt<<<dim3(32, 24), 256, 0, stream>>>(hs_f, w_f, qkv, 4096, 3072, 2048);
  norm_rope_kernel<<<12288, 256, 0, stream>>>(qkv, cosb, sinb, qw, kw, q_t, k_t, v_t);
  attn_kernel<<<dim3(16, 16), 512, 0, stream>>>(q_t, k_t, v_t, oP, mlp);
  combine_kernel<<<8192, 256, 0, stream>>>(oP, mlp, aout);
  gemm_h_nt<<<dim3(32, 16), 256, 0, stream>>>(aout, wo_f, out, 4096, 2048, 2048);
}

// Round 9
// 239.360 us; speedup vs baseline: 1.2104x; 1.0445x over previous
//
#include <hip/hip_runtime.h>
#include <hip/hip_bf16.h>
#include <stdint.h>

// Problem constants (Gemma3n attention block)
#define S_LEN 2048
#define HIDN  2048
#define NH    8
#define NKV   2
#define HD    256

typedef _Float16 v8h  __attribute__((ext_vector_type(8)));
typedef float    v4f  __attribute__((ext_vector_type(4)));
typedef float    v16f __attribute__((ext_vector_type(16)));
typedef unsigned short u16;

struct alignas(8) US4 { u16 x, y, z, w; };

__device__ __forceinline__ u16 f2h(float f) {
  union { _Float16 h; u16 u; } t; t.h = (_Float16)f; return t.u;
}
__device__ __forceinline__ float h2f(u16 u) {
  union { _Float16 h; u16 u; } t; t.u = u; return (float)t.h;
}
__device__ __forceinline__ uint32_t pk2(float a, float b) {
  return (uint32_t)f2h(a) | ((uint32_t)f2h(b) << 16);
}

template <typename T>
__device__ __forceinline__ void gload16(const T* g, void* l) {
  __builtin_amdgcn_global_load_lds(
      (const __attribute__((address_space(1))) void*)g,
      (__attribute__((address_space(3))) void*)l, 16, 0, 0);
}

// ---------------- f32 -> f16 cast, 4 elems/thread ----------------
__global__ void cvt_h_kernel(const float* __restrict__ in, u16* __restrict__ out, int n4) {
  int i = blockIdx.x * blockDim.x + threadIdx.x;
  if (i >= n4) return;
  float4 v = reinterpret_cast<const float4*>(in)[i];
  US4 o; o.x = f2h(v.x); o.y = f2h(v.y); o.z = f2h(v.z); o.w = f2h(v.w);
  reinterpret_cast<US4*>(out)[i] = o;
}

// ---------------- 8-phase-style f16 NT GEMM (T2+T3+T4+T5) --------------------
// BM = MF*32 (MF=8: 256, MF=4: 128), BN=256, BK=64. 512 thr = 8 waves (2M x 4N),
// per-wave C = (MF*16) x 64 = MF x 4 fragments of 16x16. 4 phases per K-step:
// {ds_read subtile + staged gloads -> barrier -> lgkmcnt(0) -> setprio MFMA ->
// barrier}. Staging issued phases 0-1 for kt+1 (issue-early); single vmcnt(0)
// at phase 3 (loads had >=2 phases of lead). LDS swizzle slot^=(row&7) via
// pre-permuted global source + swizzled ds_read (both-sides rule).
template <int MF, int OUT_F16>
__global__ __launch_bounds__(512, 2) void gemm256(
    const u16* __restrict__ A, const u16* __restrict__ Bm,
    void* __restrict__ C, int M, int N, int K) {
  __shared__ u16 As[2][MF * 2048];   // BM x 64
  __shared__ u16 Bs[2][16384];       // 256 x 64
  const int tid = threadIdx.x;
  const int w = tid >> 6, lane = tid & 63;
  const int wm = w >> 2, wn = w & 3;
  const int lr = lane & 15, ls = lane >> 4;
  const int m0 = blockIdx.x * (MF * 32);
  const int n0 = blockIdx.y * 256;
  const int KT = K >> 6;
  constexpr int FPP = MF / 4;        // M-frags per phase
  v4f acc[MF][4] = {};

  auto stageA = [&](int kt, int buf, int r) {
    const int idx = r * 512 + tid;
    const int row = idx >> 3, sp = idx & 7;
    const int sl = sp ^ (row & 7);
    gload16(A + (size_t)(m0 + row) * K + kt * 64 + sl * 8, (char*)As[buf] + idx * 16);
  };
  auto stageB = [&](int kt, int buf, int r) {
    const int idx = r * 512 + tid;
    const int row = idx >> 3, sp = idx & 7;
    const int sl = sp ^ (row & 7);
    gload16(Bm + (size_t)(n0 + row) * K + kt * 64 + sl * 8, (char*)Bs[buf] + idx * 16);
  };

  // prologue: stage kt=0 into buf 0
#pragma unroll
  for (int r = 0; r < MF / 2; r++) stageA(0, 0, r);
#pragma unroll
  for (int r = 0; r < 4; r++) stageB(0, 0, r);
  asm volatile("s_waitcnt vmcnt(0)" ::: "memory");
  __builtin_amdgcn_s_barrier();
  __builtin_amdgcn_sched_barrier(0);

  for (int kt = 0; kt < KT; kt++) {
    const int buf = kt & 1;
    v8h bfrag[2][4];
#pragma unroll
    for (int p = 0; p < 4; p++) {
      if (p == 0) {
#pragma unroll
        for (int kk = 0; kk < 2; kk++)
#pragma unroll
          for (int j = 0; j < 4; j++) {
            const int row = wn * 64 + j * 16 + lr;
            const int sp = (kk * 4 + ls) ^ (row & 7);
            bfrag[kk][j] = *reinterpret_cast<const v8h*>(&Bs[buf][row * 64 + sp * 8]);
          }
      }
      v8h a2[FPP][2];
#pragma unroll
      for (int ii = 0; ii < FPP; ii++)
#pragma unroll
        for (int kk = 0; kk < 2; kk++) {
          const int row = wm * MF * 16 + (p * FPP + ii) * 16 + lr;
          const int sp = (kk * 4 + ls) ^ (row & 7);
          a2[ii][kk] = *reinterpret_cast<const v8h*>(&As[buf][row * 64 + sp * 8]);
        }
      if (kt + 1 < KT) {
        if (p == 0) {
#pragma unroll
          for (int r = 0; r < MF / 2; r++) stageA(kt + 1, buf ^ 1, r);
        }
        if (p == 1) {
#pragma unroll
          for (int r = 0; r < 4; r++) stageB(kt + 1, buf ^ 1, r);
        }
      }
      if (p == 3) asm volatile("s_waitcnt vmcnt(0)" ::: "memory");
      __builtin_amdgcn_s_barrier();
      asm volatile("s_waitcnt lgkmcnt(0)" ::: "memory");
      __builtin_amdgcn_sched_barrier(0);
      __builtin_amdgcn_s_setprio(1);
#pragma unroll
      for (int ii = 0; ii < FPP; ii++)
#pragma unroll
        for (int j = 0; j < 4; j++)
#pragma unroll
          for (int kk = 0; kk < 2; kk++)
            acc[p * FPP + ii][j] = __builtin_amdgcn_mfma_f32_16x16x32_f16(
                a2[ii][kk], bfrag[kk][j], acc[p * FPP + ii][j], 0, 0, 0);
      __builtin_amdgcn_s_setprio(0);
      __builtin_amdgcn_s_barrier();
    }
  }

#pragma unroll
  for (int i = 0; i < MF; i++)
#pragma unroll
    for (int j = 0; j < 4; j++) {
      const int col = n0 + wn * 64 + j * 16 + lr;
#pragma unroll
      for (int jj = 0; jj < 4; jj++) {
        const int row = m0 + wm * MF * 16 + i * 16 + ls * 4 + jj;
        if (OUT_F16) ((u16*)C)[(size_t)row * N + col] = f2h(acc[i][j][jj]);
        else         ((float*)C)[(size_t)row * N + col] = acc[i][j][jj];
      }
    }
}

// ---------------- RMSNorm (+RoPE for Q,K), f16 in/out, V transpose -----------
__global__ __launch_bounds__(256, 4) void norm_rope_kernel(
    const u16* __restrict__ qkv, const float* __restrict__ cosb, const float* __restrict__ sinb,
    const float* __restrict__ qw, const float* __restrict__ kw,
    u16* __restrict__ q_t, u16* __restrict__ k_t, u16* __restrict__ v_t) {
  const int task = blockIdx.x * 4 + (threadIdx.x >> 6);
  const int lane = threadIdx.x & 63;
  const int unit = task % 12;
  const int ms = task / 12;           // b*S + s
  const int b = ms >> 11, s = ms & 2047;
  const int d0 = lane << 2;
  const int col0 = (unit < 8) ? unit * 256 : 2048 + (unit - 8) * 256;
  const US4 xv = *reinterpret_cast<const US4*>(qkv + (size_t)ms * 3072 + col0 + d0);
  float x[4] = { h2f(xv.x), h2f(xv.y), h2f(xv.z), h2f(xv.w) };
  float ss = x[0]*x[0] + x[1]*x[1] + x[2]*x[2] + x[3]*x[3];
#pragma unroll
  for (int m = 1; m < 64; m <<= 1) ss += __shfl_xor(ss, m, 64);
  const float r = rsqrtf(ss * (1.0f / 256.0f) + 1e-6f);
  if (unit < 10) {
    const float4 wv = *reinterpret_cast<const float4*>(((unit < 8) ? qw : kw) + d0);
    float xn[4];
    xn[0] = x[0] * r * wv.x; xn[1] = x[1] * r * wv.y;
    xn[2] = x[2] * r * wv.z; xn[3] = x[3] * r * wv.w;
    float rot[4];
#pragma unroll
    for (int j = 0; j < 4; j++) {
      const float p = __shfl(xn[j], lane ^ 32, 64);
      rot[j] = (lane < 32) ? -p : p;   // rotate_half: (-x2, x1)
    }
    const float4 c  = *reinterpret_cast<const float4*>(cosb + (size_t)ms * 256 + d0);
    const float4 sn = *reinterpret_cast<const float4*>(sinb + (size_t)ms * 256 + d0);
    US4 o;
    o.x = f2h(xn[0] * c.x + rot[0] * sn.x);
    o.y = f2h(xn[1] * c.y + rot[1] * sn.y);
    o.z = f2h(xn[2] * c.z + rot[2] * sn.z);
    o.w = f2h(xn[3] * c.w + rot[3] * sn.w);
    if (unit < 8) {
      const size_t dst = ((size_t)(b * NH + unit) * S_LEN + s) * 256 + d0;
      *reinterpret_cast<US4*>(q_t + dst) = o;
    } else {
      const size_t dst = ((size_t)(b * NKV + (unit - 8)) * S_LEN + s) * 256 + d0;
      *reinterpret_cast<US4*>(k_t + dst) = o;
    }
  } else {
    const int kvh = unit - 10;
    u16* vt = v_t + (size_t)(b * NKV + kvh) * 256 * 2048;   // [d][s] transposed
#pragma unroll
    for (int j = 0; j < 4; j++)
      vt[(size_t)(d0 + j) * 2048 + s] = f2h(x[j] * r);
  }
}

// stage one K/V tile. K: [64 kv][32 slots x 16B], slot_phys = slot_log ^ (kv&31)
// V: [256 d][8 slots x 16B],  slot_phys = slot_log ^ ((d>>2)&7)
__device__ __forceinline__ void stage_kv(
    const u16* __restrict__ kb, const u16* __restrict__ vb, int kt,
    u16* Kbuf, u16* Vbuf, int tid) {
#pragma unroll
  for (int it = 0; it < 4; it++) {
    const int i1 = tid + it * 512;
    const int kv = i1 >> 5, sp = i1 & 31;
    const int sl = sp ^ (kv & 31);
    gload16(kb + (size_t)(kt * 64 + kv) * 256 + sl * 8, (char*)Kbuf + i1 * 16);
    const int d = i1 >> 3, sp2 = i1 & 7;
    const int sl2 = sp2 ^ ((d >> 2) & 7);
    gload16(vb + (size_t)d * 2048 + kt * 64 + sl2 * 8, (char*)Vbuf + i1 * 16);
  }
}

// ---------------- causal flash attention, fp16 32x32 MFMA --------------------
// PERFECT BALANCE: grid (16 qt, 16 bh) = 256 blocks = 1/CU, all resident.
// Item A=(qtA, z=0: tiles 0..qtA) then B=(qtB=15-qtA, z=1): always 17 tiles.
__global__ __launch_bounds__(512, 2) void attn_kernel(
    const u16* __restrict__ q_t, const u16* __restrict__ k_t,
    const u16* __restrict__ v_t, u16* __restrict__ oP, float2* __restrict__ ml) {
  const int qtA = blockIdx.x;
  const int qtB = 15 - qtA;
  const int bh = blockIdx.y;
  const int b = bh >> 3, h = bh & 7, hk = h >> 2;
  const int tid = threadIdx.x;
  const int w = tid >> 6, lane = tid & 63;
  const int g = w >> 1, hf = w & 1;
  const int l31 = lane & 31, hi = lane >> 5;

  __shared__ u16 Kb[2][16384];   // 2 x 32KB [kv][slot16B] swizzled
  __shared__ u16 Vb[2][16384];   // 2 x 32KB [d][slot16B] swizzled

  const u16* qhead = q_t + (size_t)(b * NH + h) * S_LEN * 256;
  const u16* kb = k_t + (size_t)(b * NKV + hk) * S_LEN * 256;
  const u16* vb = v_t + (size_t)(b * NKV + hk) * 256 * S_LEN;

  const u16* qbA = qhead + (size_t)(qtA * 128 + g * 32 + l31) * 256;
  v8h qf[16];
#pragma unroll
  for (int f = 0; f < 16; f++)
    qf[f] = *reinterpret_cast<const v8h*>(qbA + f * 16 + hi * 8);

  v16f o[4] = {};        // O^T[d = hf*128 + dblk*32 + row(reg)][q = l31]
  float mr = -1e30f, lsum = 0.f;
  int qt_cur = qtA;

  const int nA = qtA + 1;          // item A tile count; total is always 17

  stage_kv(kb, vb, 0, Kb[0], Vb[0], tid);

  for (int s = 0; s < 17; s++) {
    const int cb = s & 1;
    const int kt = (s < nA) ? s : (qtB + 1 + s - nA);
    if (s + 1 < 17) {
      const int s1 = s + 1;
      const int ktn = (s1 < nA) ? s1 : (qtB + 1 + s1 - nA);
      stage_kv(kb, vb, ktn, Kb[cb ^ 1], Vb[cb ^ 1], tid);
      asm volatile("s_waitcnt vmcnt(8)" ::: "memory");
    } else {
      asm volatile("s_waitcnt vmcnt(0)" ::: "memory");
    }
    __builtin_amdgcn_s_barrier();
    __builtin_amdgcn_sched_barrier(0);

    if (s == nA) {
      // ---- item boundary: flush A's partial, reset state, load B's Q ----
      const size_t rowi = (((size_t)bh) * 16 + qtA) * 128 + g * 32 + l31;  // z=0
      u16* ob = oP + rowi * 256;
#pragma unroll
      for (int dblk = 0; dblk < 4; dblk++)
#pragma unroll
        for (int rr = 0; rr < 4; rr++) {
          const int dbase = hf * 128 + dblk * 32 + rr * 8 + hi * 4;
          uint2 pw;
          pw.x = pk2(o[dblk][rr * 4 + 0], o[dblk][rr * 4 + 1]);
          pw.y = pk2(o[dblk][rr * 4 + 2], o[dblk][rr * 4 + 3]);
          *reinterpret_cast<uint2*>(ob + dbase) = pw;
        }
      if (hf == 0 && lane < 32)
        ml[rowi] = make_float2(mr, lsum);
      const u16* qbB = qhead + (size_t)(qtB * 128 + g * 32 + l31) * 256;
#pragma unroll
      for (int f = 0; f < 16; f++)
        qf[f] = *reinterpret_cast<const v8h*>(qbB + f * 16 + hi * 8);
#pragma unroll
      for (int dblk = 0; dblk < 4; dblk++) o[dblk] = v16f{};
      mr = -1e30f; lsum = 0.f;
      qt_cur = qtB;
    }

    // QK^T swapped: S^T[kv][q], kv = nkv*32 + (r&3)+8*(r>>2)+4*hi, q = l31
    v16f s0 = {}, s1 = {};
    __builtin_amdgcn_s_setprio(1);
#pragma unroll
    for (int ds = 0; ds < 16; ds++) {
      const int sp = (ds * 2 + hi) ^ l31;
      const v8h kf0 = *reinterpret_cast<const v8h*>(&Kb[cb][l31 * 256 + sp * 8]);
      const v8h kf1 = *reinterpret_cast<const v8h*>(&Kb[cb][(32 + l31) * 256 + sp * 8]);
      s0 = __builtin_amdgcn_mfma_f32_32x32x16_f16(kf0, qf[ds], s0, 0, 0, 0);
      s1 = __builtin_amdgcn_mfma_f32_32x32x16_f16(kf1, qf[ds], s1, 0, 0, 0);
    }
    __builtin_amdgcn_s_setprio(0);
    if (kt >= 2 * qt_cur) {   // diagonal tile: causal mask
      const int qg = qt_cur * 128 + g * 32 + l31;
#pragma unroll
      for (int r = 0; r < 16; r++) {
        const int kvr = kt * 64 + (r & 3) + 8 * (r >> 2) + 4 * hi;
        if (kvr > qg) s0[r] = -1e30f;
        if (kvr + 32 > qg) s1[r] = -1e30f;
      }
    }
    // in-register online softmax (lane owns one q-row's 32 kv; partner via shfl)
    float pm = s0[0];
#pragma unroll
    for (int r = 1; r < 16; r++) pm = fmaxf(pm, s0[r]);
#pragma unroll
    for (int r = 0; r < 16; r++) pm = fmaxf(pm, s1[r]);
    pm = fmaxf(pm, __shfl_xor(pm, 32, 64));
    if (!__all(pm - mr <= 8.0f)) {       // T13 defer-max
      const float mn = fmaxf(mr, pm);
      const float sc = __expf(mr - mn);
      mr = mn;
      lsum *= sc;
#pragma unroll
      for (int dblk = 0; dblk < 4; dblk++)
#pragma unroll
        for (int r = 0; r < 16; r++) o[dblk][r] *= sc;
    }
    float rs = 0.f;
#pragma unroll
    for (int r = 0; r < 16; r++) { s0[r] = __expf(s0[r] - mr); rs += s0[r]; }
#pragma unroll
    for (int r = 0; r < 16; r++) { s1[r] = __expf(s1[r] - mr); rs += s1[r]; }
    rs += __shfl_xor(rs, 32, 64);
    lsum += rs;
    // pack P^T pairs and exchange lane-halves (kv +-4 lives in lane^32)
    uint32_t pka[2][8], pkx[2][8];
#pragma unroll
    for (int u = 0; u < 8; u++) {
      const int r = (u & 1) * 2 + (u >> 1) * 4;
      pka[0][u] = pk2(s0[r], s0[r + 1]);
      pka[1][u] = pk2(s1[r], s1[r + 1]);
    }
#pragma unroll
    for (int n = 0; n < 2; n++)
#pragma unroll
      for (int u = 0; u < 8; u++)
        pkx[n][u] = (uint32_t)__shfl_xor((int)pka[n][u], 32, 64);
    // B-fragments for PV: P^T[kv = sblk*16 + hi*8 + j][q = l31]
    v8h bfr[4];
#pragma unroll
    for (int sblk = 0; sblk < 4; sblk++) {
      const int n = sblk >> 1, base = (sblk & 1) * 4;
      union { uint32_t u[4]; v8h h; } t;
      if (hi == 0) {
        t.u[0] = pka[n][base];     t.u[1] = pka[n][base + 1];
        t.u[2] = pkx[n][base];     t.u[3] = pkx[n][base + 1];
      } else {
        t.u[0] = pkx[n][base + 2]; t.u[1] = pkx[n][base + 3];
        t.u[2] = pka[n][base + 2]; t.u[3] = pka[n][base + 3];
      }
      bfr[sblk] = t.h;
    }
    // PV: O^T[d][q] += V^T[d][kv] * P^T[kv][q], d-half hf
    __builtin_amdgcn_s_setprio(1);
#pragma unroll
    for (int dblk = 0; dblk < 4; dblk++) {
      const int d = hf * 128 + dblk * 32 + l31;
#pragma unroll
      for (int sblk = 0; sblk < 4; sblk++) {
        const int sp = (sblk * 2 + hi) ^ ((d >> 2) & 7);
        const v8h vf = *reinterpret_cast<const v8h*>(&Vb[cb][d * 64 + sp * 8]);
        o[dblk] = __builtin_amdgcn_mfma_f32_32x32x16_f16(vf, bfr[sblk], o[dblk], 0, 0, 0);
      }
    }
    __builtin_amdgcn_s_setprio(0);
    __builtin_amdgcn_s_barrier();
    __builtin_amdgcn_sched_barrier(0);
  }

  // write item B's unnormalized partial (z=1) + (m, l)
  const size_t rowi = (((size_t)(16 + bh)) * 16 + qtB) * 128 + g * 32 + l31;
  u16* ob = oP + rowi * 256;
#pragma unroll
  for (int dblk = 0; dblk < 4; dblk++)
#pragma unroll
    for (int rr = 0; rr < 4; rr++) {
      const int dbase = hf * 128 + dblk * 32 + rr * 8 + hi * 4;
      uint2 pw;
      pw.x = pk2(o[dblk][rr * 4 + 0], o[dblk][rr * 4 + 1]);
      pw.y = pk2(o[dblk][rr * 4 + 2], o[dblk][rr * 4 + 3]);
      *reinterpret_cast<uint2*>(ob + dbase) = pw;
    }
  if (hf == 0 && lane < 32)
    ml[rowi] = make_float2(mr, lsum);
}

// ---------------- split-K combine: merge 2 partials -> aout f16 --------------
__global__ __launch_bounds__(256, 8) void combine_kernel(
    const u16* __restrict__ oP, const float2* __restrict__ ml,
    u16* __restrict__ aout) {
  const int wid = threadIdx.x >> 6, lane = threadIdx.x & 63;
  const int R = blockIdx.x * 4 + wid;          // 0..32767 = (bh, qt, row)
  const int bh = R >> 11, rem = R & 2047, qt = rem >> 7, row = rem & 127;
  const int b = bh >> 3, h = bh & 7;
  const size_t i0 = (((size_t)bh)      * 16 + qt) * 128 + row;
  const size_t i1 = (((size_t)(16+bh)) * 16 + qt) * 128 + row;
  const float2 m0 = ml[i0], m1 = ml[i1];
  const float ms = fmaxf(m0.x, m1.x);
  const float f0 = __expf(m0.x - ms), f1 = __expf(m1.x - ms);
  const float inv = 1.0f / (m0.y * f0 + m1.y * f1);
  const US4 a = reinterpret_cast<const US4*>(oP + i0 * 256)[lane];
  const US4 c = reinterpret_cast<const US4*>(oP + i1 * 256)[lane];
  US4 o;
  o.x = f2h((h2f(a.x) * f0 + h2f(c.x) * f1) * inv);
  o.y = f2h((h2f(a.y) * f0 + h2f(c.y) * f1) * inv);
  o.z = f2h((h2f(a.z) * f0 + h2f(c.z) * f1) * inv);
  o.w = f2h((h2f(a.w) * f0 + h2f(c.w) * f1) * inv);
  u16* dst = aout + ((size_t)(b * 2048 + qt * 128 + row)) * 2048 + h * 256 + lane * 4;
  *reinterpret_cast<US4*>(dst) = o;
}

extern "C" void kernel_launch(void* const* d_in, const int* in_sizes, int n_in,
                              void* d_out, int out_size, void* d_ws, size_t ws_size,
                              hipStream_t stream) {
  const float* hs   = (const float*)d_in[0];
  const float* cosb = (const float*)d_in[1];
  const float* sinb = (const float*)d_in[2];
  // d_in[3] attention_mask: exactly causal -> applied analytically in attn_kernel
  const float* Wq = (const float*)d_in[4];
  const float* Wk = (const float*)d_in[5];
  const float* Wv = (const float*)d_in[6];
  const float* Wo = (const float*)d_in[7];
  const float* qw = (const float*)d_in[8];
  const float* kw = (const float*)d_in[9];
  float* out = (float*)d_out;

  char* ws = (char*)d_ws;
  u16* hs_f = (u16*)(ws + 0);            // 16.78MB f16 (4096x2048)
  u16* w_f  = (u16*)(ws + 16777216);     // 12.58MB f16 (Wq|Wk|Wv rows, 3072x2048)
  u16* wo_f = (u16*)(ws + 29360128);     //  8.39MB f16 (2048x2048)
  u16* qkvh = (u16*)(ws + 37748736);     // 25.17MB f16 (4096x3072, ends 62,914,560)
  u16* q_t  = (u16*)(ws + 88080384);     // 16.78MB f16 (B,NH,S,HD)
  u16* k_t  = (u16*)(ws + 104857600);    //  4.19MB f16 (B,NKV,S,HD)
  u16* v_t  = (u16*)(ws + 109051904);    //  4.19MB f16 (B,NKV,HD,S)  ends 113.2MB
  // late-phase aliases (producers of aliased regions complete first)
  u16* oP   = (u16*)(ws + 37748736);     // 33.55MB f16 partials (aliases qkvh)
  float2* mlp = (float2*)(ws + 71303168);// 0.52MB (right after oP)
  u16* aout = (u16*)(ws + 0);            // 16.78MB f16 (aliases hs_f, gemm1 done)

  cvt_h_kernel<<<8192, 256, 0, stream>>>(hs, hs_f, 2097152);
  cvt_h_kernel<<<4096, 256, 0, stream>>>(Wq, w_f,           1048576);
  cvt_h_kernel<<<1024, 256, 0, stream>>>(Wk, w_f + 4194304, 262144);
  cvt_h_kernel<<<1024, 256, 0, stream>>>(Wv, w_f + 5242880, 262144);
  cvt_h_kernel<<<4096, 256, 0, stream>>>(Wo, wo_f,          1048576);

  gemm256<8, 1><<<dim3(16, 12), 512, 0, stream>>>(hs_f, w_f, qkvh, 4096, 3072, 2048);
  norm_rope_kernel<<<12288, 256, 0, stream>>>(qkvh, cosb, sinb, qw, kw, q_t, k_t, v_t);
  attn_kernel<<<dim3(16, 16), 512, 0, stream>>>(q_t, k_t, v_t, oP, mlp);
  combine_kernel<<<8192, 256, 0, stream>>>(oP, mlp, aout);
  gemm256<4, 0><<<dim3(32, 8), 512, 0, stream>>>(aout, wo_f, out, 4096, 2048, 2048);
}

// Round 11
// 230.204 us; speedup vs baseline: 1.2586x; 1.0398x over previous
//
#include <hip/hip_runtime.h>
#include <hip/hip_bf16.h>
#include <stdint.h>

// Problem constants (Gemma3n attention block)
#define S_LEN 2048
#define HIDN  2048
#define NH    8
#define NKV   2
#define HD    256

typedef _Float16 v8h  __attribute__((ext_vector_type(8)));
typedef float    v4f  __attribute__((ext_vector_type(4)));
typedef float    v16f __attribute__((ext_vector_type(16)));
typedef unsigned short u16;

struct alignas(8) US4 { u16 x, y, z, w; };

__device__ __forceinline__ u16 f2h(float f) {
  union { _Float16 h; u16 u; } t; t.h = (_Float16)f; return t.u;
}
__device__ __forceinline__ float h2f(u16 u) {
  union { _Float16 h; u16 u; } t; t.u = u; return (float)t.h;
}
__device__ __forceinline__ uint32_t pk2(float a, float b) {
  return (uint32_t)f2h(a) | ((uint32_t)f2h(b) << 16);
}

template <typename T>
__device__ __forceinline__ void gload16(const T* g, void* l) {
  __builtin_amdgcn_global_load_lds(
      (const __attribute__((address_space(1))) void*)g,
      (__attribute__((address_space(3))) void*)l, 16, 0, 0);
}

__device__ __forceinline__ void cvt_quad(const float* src, u16* dst) {
  float4 v = *reinterpret_cast<const float4*>(src);
  US4 o; o.x = f2h(v.x); o.y = f2h(v.y); o.z = f2h(v.z); o.w = f2h(v.w);
  *reinterpret_cast<US4*>(dst) = o;
}

// ---------------- fused f32 -> f16 cast for all 5 inputs ----------------
// quad segments: hs 2097152 | Wq 1048576 | Wk 262144 | Wv 262144 | Wo 1048576
// total 4718592 quads = 18432 blocks x 256
__global__ void cvt_all_kernel(
    const float* __restrict__ hs, const float* __restrict__ Wq,
    const float* __restrict__ Wk, const float* __restrict__ Wv,
    const float* __restrict__ Wo,
    u16* __restrict__ hs_f, u16* __restrict__ w_f, u16* __restrict__ wo_f) {
  int j = blockIdx.x * blockDim.x + threadIdx.x;   // quad index
  if (j < 2097152) { cvt_quad(hs + (size_t)j * 4, hs_f + (size_t)j * 4); return; }
  j -= 2097152;
  if (j < 1048576) { cvt_quad(Wq + (size_t)j * 4, w_f + (size_t)j * 4); return; }
  j -= 1048576;
  if (j < 262144) { cvt_quad(Wk + (size_t)j * 4, w_f + 4194304 + (size_t)j * 4); return; }
  j -= 262144;
  if (j < 262144) { cvt_quad(Wv + (size_t)j * 4, w_f + 5242880 + (size_t)j * 4); return; }
  j -= 262144;
  cvt_quad(Wo + (size_t)j * 4, wo_f + (size_t)j * 4);
}

// ---------------- 8-phase-style f16 NT GEMM (T2+T3+T4+T5) --------------------
// BM = MF*32, BN = NFR*64. 512 thr = 8 waves (2M x 4N), per-wave C =
// (MF*16) x (NFR*16). 4 phases per K-step: {ds_read subtile + staged gloads ->
// barrier -> lgkmcnt(0) -> setprio MFMA -> barrier}. Staging issued phases 0-1
// for kt+1 (issue-early); single vmcnt(0) at phase 3. LDS swizzle slot^=(row&7)
// via pre-permuted global source + swizzled ds_read (both-sides rule).
template <int MF, int NFR, int OUT_F16>
__global__ __launch_bounds__(512, 2) void gemm256(
    const u16* __restrict__ A, const u16* __restrict__ Bm,
    void* __restrict__ C, int M, int N, int K) {
  __shared__ u16 As[2][MF * 2048];    // BM x 64
  __shared__ u16 Bs[2][NFR * 4096];   // BN x 64
  const int tid = threadIdx.x;
  const int w = tid >> 6, lane = tid & 63;
  const int wm = w >> 2, wn = w & 3;
  const int lr = lane & 15, ls = lane >> 4;
  const int m0 = blockIdx.x * (MF * 32);
  const int n0 = blockIdx.y * (NFR * 64);
  const int KT = K >> 6;
  constexpr int FPP = MF / 4;        // M-frags per phase
  v4f acc[MF][NFR] = {};

  auto stageA = [&](int kt, int buf, int r) {
    const int idx = r * 512 + tid;
    const int row = idx >> 3, sp = idx & 7;
    const int sl = sp ^ (row & 7);
    gload16(A + (size_t)(m0 + row) * K + kt * 64 + sl * 8, (char*)As[buf] + idx * 16);
  };
  auto stageB = [&](int kt, int buf, int r) {
    const int idx = r * 512 + tid;
    const int row = idx >> 3, sp = idx & 7;
    const int sl = sp ^ (row & 7);
    gload16(Bm + (size_t)(n0 + row) * K + kt * 64 + sl * 8, (char*)Bs[buf] + idx * 16);
  };

  // prologue: stage kt=0 into buf 0
#pragma unroll
  for (int r = 0; r < MF / 2; r++) stageA(0, 0, r);
#pragma unroll
  for (int r = 0; r < NFR; r++) stageB(0, 0, r);
  asm volatile("s_waitcnt vmcnt(0)" ::: "memory");
  __builtin_amdgcn_s_barrier();
  __builtin_amdgcn_sched_barrier(0);

  for (int kt = 0; kt < KT; kt++) {
    const int buf = kt & 1;
    v8h bfrag[2][NFR];
#pragma unroll
    for (int p = 0; p < 4; p++) {
      if (p == 0) {
#pragma unroll
        for (int kk = 0; kk < 2; kk++)
#pragma unroll
          for (int j = 0; j < NFR; j++) {
            const int row = wn * (NFR * 16) + j * 16 + lr;
            const int sp = (kk * 4 + ls) ^ (row & 7);
            bfrag[kk][j] = *reinterpret_cast<const v8h*>(&Bs[buf][row * 64 + sp * 8]);
          }
      }
      v8h a2[FPP][2];
#pragma unroll
      for (int ii = 0; ii < FPP; ii++)
#pragma unroll
        for (int kk = 0; kk < 2; kk++) {
          const int row = wm * MF * 16 + (p * FPP + ii) * 16 + lr;
          const int sp = (kk * 4 + ls) ^ (row & 7);
          a2[ii][kk] = *reinterpret_cast<const v8h*>(&As[buf][row * 64 + sp * 8]);
        }
      if (kt + 1 < KT) {
        if (p == 0) {
#pragma unroll
          for (int r = 0; r < MF / 2; r++) stageA(kt + 1, buf ^ 1, r);
        }
        if (p == 1) {
#pragma unroll
          for (int r = 0; r < NFR; r++) stageB(kt + 1, buf ^ 1, r);
        }
      }
      if (p == 3) asm volatile("s_waitcnt vmcnt(0)" ::: "memory");
      __builtin_amdgcn_s_barrier();
      asm volatile("s_waitcnt lgkmcnt(0)" ::: "memory");
      __builtin_amdgcn_sched_barrier(0);
      __builtin_amdgcn_s_setprio(1);
#pragma unroll
      for (int ii = 0; ii < FPP; ii++)
#pragma unroll
        for (int j = 0; j < NFR; j++)
#pragma unroll
          for (int kk = 0; kk < 2; kk++)
            acc[p * FPP + ii][j] = __builtin_amdgcn_mfma_f32_16x16x32_f16(
                a2[ii][kk], bfrag[kk][j], acc[p * FPP + ii][j], 0, 0, 0);
      __builtin_amdgcn_s_setprio(0);
      __builtin_amdgcn_s_barrier();
    }
  }

#pragma unroll
  for (int i = 0; i < MF; i++)
#pragma unroll
    for (int j = 0; j < NFR; j++) {
      const int col = n0 + wn * (NFR * 16) + j * 16 + lr;
#pragma unroll
      for (int jj = 0; jj < 4; jj++) {
        const int row = m0 + wm * MF * 16 + i * 16 + ls * 4 + jj;
        if (OUT_F16) ((u16*)C)[(size_t)row * N + col] = f2h(acc[i][j][jj]);
        else         ((float*)C)[(size_t)row * N + col] = acc[i][j][jj];
      }
    }
}

// ---------------- RMSNorm (+RoPE for Q,K), f16 in/out, V transpose -----------
__global__ __launch_bounds__(256, 4) void norm_rope_kernel(
    const u16* __restrict__ qkv, const float* __restrict__ cosb, const float* __restrict__ sinb,
    const float* __restrict__ qw, const float* __restrict__ kw,
    u16* __restrict__ q_t, u16* __restrict__ k_t, u16* __restrict__ v_t) {
  const int task = blockIdx.x * 4 + (threadIdx.x >> 6);
  const int lane = threadIdx.x & 63;
  const int unit = task % 12;
  const int ms = task / 12;           // b*S + s
  const int b = ms >> 11, s = ms & 2047;
  const int d0 = lane << 2;
  const int col0 = (unit < 8) ? unit * 256 : 2048 + (unit - 8) * 256;
  const US4 xv = *reinterpret_cast<const US4*>(qkv + (size_t)ms * 3072 + col0 + d0);
  float x[4] = { h2f(xv.x), h2f(xv.y), h2f(xv.z), h2f(xv.w) };
  float ss = x[0]*x[0] + x[1]*x[1] + x[2]*x[2] + x[3]*x[3];
#pragma unroll
  for (int m = 1; m < 64; m <<= 1) ss += __shfl_xor(ss, m, 64);
  const float r = rsqrtf(ss * (1.0f / 256.0f) + 1e-6f);
  if (unit < 10) {
    const float4 wv = *reinterpret_cast<const float4*>(((unit < 8) ? qw : kw) + d0);
    float xn[4];
    xn[0] = x[0] * r * wv.x; xn[1] = x[1] * r * wv.y;
    xn[2] = x[2] * r * wv.z; xn[3] = x[3] * r * wv.w;
    float rot[4];
#pragma unroll
    for (int j = 0; j < 4; j++) {
      const float p = __shfl(xn[j], lane ^ 32, 64);
      rot[j] = (lane < 32) ? -p : p;   // rotate_half: (-x2, x1)
    }
    const float4 c  = *reinterpret_cast<const float4*>(cosb + (size_t)ms * 256 + d0);
    const float4 sn = *reinterpret_cast<const float4*>(sinb + (size_t)ms * 256 + d0);
    US4 o;
    o.x = f2h(xn[0] * c.x + rot[0] * sn.x);
    o.y = f2h(xn[1] * c.y + rot[1] * sn.y);
    o.z = f2h(xn[2] * c.z + rot[2] * sn.z);
    o.w = f2h(xn[3] * c.w + rot[3] * sn.w);
    if (unit < 8) {
      const size_t dst = ((size_t)(b * NH + unit) * S_LEN + s) * 256 + d0;
      *reinterpret_cast<US4*>(q_t + dst) = o;
    } else {
      const size_t dst = ((size_t)(b * NKV + (unit - 8)) * S_LEN + s) * 256 + d0;
      *reinterpret_cast<US4*>(k_t + dst) = o;
    }
  } else {
    const int kvh = unit - 10;
    u16* vt = v_t + (size_t)(b * NKV + kvh) * 256 * 2048;   // [d][s] transposed
#pragma unroll
    for (int j = 0; j < 4; j++)
      vt[(size_t)(d0 + j) * 2048 + s] = f2h(x[j] * r);
  }
}

// stage one K/V tile. K: [64 kv][32 slots x 16B], slot_phys = slot_log ^ (kv&31)
// V: [256 d][8 slots x 16B],  slot_phys = slot_log ^ ((d>>2)&7)
__device__ __forceinline__ void stage_kv(
    const u16* __restrict__ kb, const u16* __restrict__ vb, int kt,
    u16* Kbuf, u16* Vbuf, int tid) {
#pragma unroll
  for (int it = 0; it < 4; it++) {
    const int i1 = tid + it * 512;
    const int kv = i1 >> 5, sp = i1 & 31;
    const int sl = sp ^ (kv & 31);
    gload16(kb + (size_t)(kt * 64 + kv) * 256 + sl * 8, (char*)Kbuf + i1 * 16);
    const int d = i1 >> 3, sp2 = i1 & 7;
    const int sl2 = sp2 ^ ((d >> 2) & 7);
    gload16(vb + (size_t)d * 2048 + kt * 64 + sl2 * 8, (char*)Vbuf + i1 * 16);
  }
}

// ---------------- causal flash attention, fp16 32x32 MFMA --------------------
// PERFECT BALANCE: grid (16 qt, 16 bh) = 256 blocks = 1/CU, all resident.
// Item A=(qtA, z=0: tiles 0..qtA) then B=(qtB=15-qtA, z=1): always 17 tiles.
__global__ __launch_bounds__(512, 2) void attn_kernel(
    const u16* __restrict__ q_t, const u16* __restrict__ k_t,
    const u16* __restrict__ v_t, u16* __restrict__ oP, float2* __restrict__ ml) {
  const int qtA = blockIdx.x;
  const int qtB = 15 - qtA;
  const int bh = blockIdx.y;
  const int b = bh >> 3, h = bh & 7, hk = h >> 2;
  const int tid = threadIdx.x;
  const int w = tid >> 6, lane = tid & 63;
  const int g = w >> 1, hf = w & 1;
  const int l31 = lane & 31, hi = lane >> 5;

  __shared__ u16 Kb[2][16384];   // 2 x 32KB [kv][slot16B] swizzled
  __shared__ u16 Vb[2][16384];   // 2 x 32KB [d][slot16B] swizzled

  const u16* qhead = q_t + (size_t)(b * NH + h) * S_LEN * 256;
  const u16* kb = k_t + (size_t)(b * NKV + hk) * S_LEN * 256;
  const u16* vb = v_t + (size_t)(b * NKV + hk) * 256 * S_LEN;

  const u16* qbA = qhead + (size_t)(qtA * 128 + g * 32 + l31) * 256;
  v8h qf[16];
#pragma unroll
  for (int f = 0; f < 16; f++)
    qf[f] = *reinterpret_cast<const v8h*>(qbA + f * 16 + hi * 8);

  v16f o[4] = {};        // O^T[d = hf*128 + dblk*32 + row(reg)][q = l31]
  float mr = -1e30f, lsum = 0.f;
  int qt_cur = qtA;

  const int nA = qtA + 1;          // item A tile count; total is always 17

  stage_kv(kb, vb, 0, Kb[0], Vb[0], tid);

  for (int s = 0; s < 17; s++) {
    const int cb = s & 1;
    const int kt = (s < nA) ? s : (qtB + 1 + s - nA);
    if (s + 1 < 17) {
      const int s1 = s + 1;
      const int ktn = (s1 < nA) ? s1 : (qtB + 1 + s1 - nA);
      stage_kv(kb, vb, ktn, Kb[cb ^ 1], Vb[cb ^ 1], tid);
      asm volatile("s_waitcnt vmcnt(8)" ::: "memory");
    } else {
      asm volatile("s_waitcnt vmcnt(0)" ::: "memory");
    }
    __builtin_amdgcn_s_barrier();
    __builtin_amdgcn_sched_barrier(0);

    if (s == nA) {
      // ---- item boundary: flush A's partial, reset state, load B's Q ----
      const size_t rowi = (((size_t)bh) * 16 + qtA) * 128 + g * 32 + l31;  // z=0
      u16* ob = oP + rowi * 256;
#pragma unroll
      for (int dblk = 0; dblk < 4; dblk++)
#pragma unroll
        for (int rr = 0; rr < 4; rr++) {
          const int dbase = hf * 128 + dblk * 32 + rr * 8 + hi * 4;
          uint2 pw;
          pw.x = pk2(o[dblk][rr * 4 + 0], o[dblk][rr * 4 + 1]);
          pw.y = pk2(o[dblk][rr * 4 + 2], o[dblk][rr * 4 + 3]);
          *reinterpret_cast<uint2*>(ob + dbase) = pw;
        }
      if (hf == 0 && lane < 32)
        ml[rowi] = make_float2(mr, lsum);
      const u16* qbB = qhead + (size_t)(qtB * 128 + g * 32 + l31) * 256;
#pragma unroll
      for (int f = 0; f < 16; f++)
        qf[f] = *reinterpret_cast<const v8h*>(qbB + f * 16 + hi * 8);
#pragma unroll
      for (int dblk = 0; dblk < 4; dblk++) o[dblk] = v16f{};
      mr = -1e30f; lsum = 0.f;
      qt_cur = qtB;
    }

    // QK^T swapped: S^T[kv][q], kv = nkv*32 + (r&3)+8*(r>>2)+4*hi, q = l31
    v16f s0 = {}, s1 = {};
    __builtin_amdgcn_s_setprio(1);
#pragma unroll
    for (int ds = 0; ds < 16; ds++) {
      const int sp = (ds * 2 + hi) ^ l31;
      const v8h kf0 = *reinterpret_cast<const v8h*>(&Kb[cb][l31 * 256 + sp * 8]);
      const v8h kf1 = *reinterpret_cast<const v8h*>(&Kb[cb][(32 + l31) * 256 + sp * 8]);
      s0 = __builtin_amdgcn_mfma_f32_32x32x16_f16(kf0, qf[ds], s0, 0, 0, 0);
      s1 = __builtin_amdgcn_mfma_f32_32x32x16_f16(kf1, qf[ds], s1, 0, 0, 0);
    }
    __builtin_amdgcn_s_setprio(0);
    if (kt >= 2 * qt_cur) {   // diagonal tile: causal mask
      const int qg = qt_cur * 128 + g * 32 + l31;
#pragma unroll
      for (int r = 0; r < 16; r++) {
        const int kvr = kt * 64 + (r & 3) + 8 * (r >> 2) + 4 * hi;
        if (kvr > qg) s0[r] = -1e30f;
        if (kvr + 32 > qg) s1[r] = -1e30f;
      }
    }
    // in-register online softmax (lane owns one q-row's 32 kv; partner via shfl)
    float pm = s0[0];
#pragma unroll
    for (int r = 1; r < 16; r++) pm = fmaxf(pm, s0[r]);
#pragma unroll
    for (int r = 0; r < 16; r++) pm = fmaxf(pm, s1[r]);
    pm = fmaxf(pm, __shfl_xor(pm, 32, 64));
    if (!__all(pm - mr <= 8.0f)) {       // T13 defer-max
      const float mn = fmaxf(mr, pm);
      const float sc = __expf(mr - mn);
      mr = mn;
      lsum *= sc;
#pragma unroll
      for (int dblk = 0; dblk < 4; dblk++)
#pragma unroll
        for (int r = 0; r < 16; r++) o[dblk][r] *= sc;
    }
    float rs = 0.f;
#pragma unroll
    for (int r = 0; r < 16; r++) { s0[r] = __expf(s0[r] - mr); rs += s0[r]; }
#pragma unroll
    for (int r = 0; r < 16; r++) { s1[r] = __expf(s1[r] - mr); rs += s1[r]; }
    rs += __shfl_xor(rs, 32, 64);
    lsum += rs;
    // pack P^T pairs and exchange lane-halves (kv +-4 lives in lane^32)
    uint32_t pka[2][8], pkx[2][8];
#pragma unroll
    for (int u = 0; u < 8; u++) {
      const int r = (u & 1) * 2 + (u >> 1) * 4;
      pka[0][u] = pk2(s0[r], s0[r + 1]);
      pka[1][u] = pk2(s1[r], s1[r + 1]);
    }
#pragma unroll
    for (int n = 0; n < 2; n++)
#pragma unroll
      for (int u = 0; u < 8; u++)
        pkx[n][u] = (uint32_t)__shfl_xor((int)pka[n][u], 32, 64);
    // B-fragments for PV: P^T[kv = sblk*16 + hi*8 + j][q = l31]
    v8h bfr[4];
#pragma unroll
    for (int sblk = 0; sblk < 4; sblk++) {
      const int n = sblk >> 1, base = (sblk & 1) * 4;
      union { uint32_t u[4]; v8h h; } t;
      if (hi == 0) {
        t.u[0] = pka[n][base];     t.u[1] = pka[n][base + 1];
        t.u[2] = pkx[n][base];     t.u[3] = pkx[n][base + 1];
      } else {
        t.u[0] = pkx[n][base + 2]; t.u[1] = pkx[n][base + 3];
        t.u[2] = pka[n][base + 2]; t.u[3] = pka[n][base + 3];
      }
      bfr[sblk] = t.h;
    }
    // PV: O^T[d][q] += V^T[d][kv] * P^T[kv][q], d-half hf
    __builtin_amdgcn_s_setprio(1);
#pragma unroll
    for (int dblk = 0; dblk < 4; dblk++) {
      const int d = hf * 128 + dblk * 32 + l31;
#pragma unroll
      for (int sblk = 0; sblk < 4; sblk++) {
        const int sp = (sblk * 2 + hi) ^ ((d >> 2) & 7);
        const v8h vf = *reinterpret_cast<const v8h*>(&Vb[cb][d * 64 + sp * 8]);
        o[dblk] = __builtin_amdgcn_mfma_f32_32x32x16_f16(vf, bfr[sblk], o[dblk], 0, 0, 0);
      }
    }
    __builtin_amdgcn_s_setprio(0);
    __builtin_amdgcn_s_barrier();
    __builtin_amdgcn_sched_barrier(0);
  }

  // write item B's unnormalized partial (z=1) + (m, l)
  const size_t rowi = (((size_t)(16 + bh)) * 16 + qtB) * 128 + g * 32 + l31;
  u16* ob = oP + rowi * 256;
#pragma unroll
  for (int dblk = 0; dblk < 4; dblk++)
#pragma unroll
    for (int rr = 0; rr < 4; rr++) {
      const int dbase = hf * 128 + dblk * 32 + rr * 8 + hi * 4;
      uint2 pw;
      pw.x = pk2(o[dblk][rr * 4 + 0], o[dblk][rr * 4 + 1]);
      pw.y = pk2(o[dblk][rr * 4 + 2], o[dblk][rr * 4 + 3]);
      *reinterpret_cast<uint2*>(ob + dbase) = pw;
    }
  if (hf == 0 && lane < 32)
    ml[rowi] = make_float2(mr, lsum);
}

// ---------------- split-K combine: merge 2 partials -> aout f16 --------------
__global__ __launch_bounds__(256, 8) void combine_kernel(
    const u16* __restrict__ oP, const float2* __restrict__ ml,
    u16* __restrict__ aout) {
  const int wid = threadIdx.x >> 6, lane = threadIdx.x & 63;
  const int R = blockIdx.x * 4 + wid;          // 0..32767 = (bh, qt, row)
  const int bh = R >> 11, rem = R & 2047, qt = rem >> 7, row = rem & 127;
  const int b = bh >> 3, h = bh & 7;
  const size_t i0 = (((size_t)bh)      * 16 + qt) * 128 + row;
  const size_t i1 = (((size_t)(16+bh)) * 16 + qt) * 128 + row;
  const float2 m0 = ml[i0], m1 = ml[i1];
  const float ms = fmaxf(m0.x, m1.x);
  const float f0 = __expf(m0.x - ms), f1 = __expf(m1.x - ms);
  const float inv = 1.0f / (m0.y * f0 + m1.y * f1);
  const US4 a = reinterpret_cast<const US4*>(oP + i0 * 256)[lane];
  const US4 c = reinterpret_cast<const US4*>(oP + i1 * 256)[lane];
  US4 o;
  o.x = f2h((h2f(a.x) * f0 + h2f(c.x) * f1) * inv);
  o.y = f2h((h2f(a.y) * f0 + h2f(c.y) * f1) * inv);
  o.z = f2h((h2f(a.z) * f0 + h2f(c.z) * f1) * inv);
  o.w = f2h((h2f(a.w) * f0 + h2f(c.w) * f1) * inv);
  u16* dst = aout + ((size_t)(b * 2048 + qt * 128 + row)) * 2048 + h * 256 + lane * 4;
  *reinterpret_cast<US4*>(dst) = o;
}

extern "C" void kernel_launch(void* const* d_in, const int* in_sizes, int n_in,
                              void* d_out, int out_size, void* d_ws, size_t ws_size,
                              hipStream_t stream) {
  const float* hs   = (const float*)d_in[0];
  const float* cosb = (const float*)d_in[1];
  const float* sinb = (const float*)d_in[2];
  // d_in[3] attention_mask: exactly causal -> applied analytically in attn_kernel
  const float* Wq = (const float*)d_in[4];
  const float* Wk = (const float*)d_in[5];
  const float* Wv = (const float*)d_in[6];
  const float* Wo = (const float*)d_in[7];
  const float* qw = (const float*)d_in[8];
  const float* kw = (const float*)d_in[9];
  float* out = (float*)d_out;

  char* ws = (char*)d_ws;
  u16* hs_f = (u16*)(ws + 0);            // 16.78MB f16 (4096x2048)
  u16* w_f  = (u16*)(ws + 16777216);     // 12.58MB f16 (Wq|Wk|Wv rows, 3072x2048)
  u16* wo_f = (u16*)(ws + 29360128);     //  8.39MB f16 (2048x2048)
  u16* qkvh = (u16*)(ws + 37748736);     // 25.17MB f16 (4096x3072, ends 62,914,560)
  u16* q_t  = (u16*)(ws + 88080384);     // 16.78MB f16 (B,NH,S,HD)
  u16* k_t  = (u16*)(ws + 104857600);    //  4.19MB f16 (B,NKV,S,HD)
  u16* v_t  = (u16*)(ws + 109051904);    //  4.19MB f16 (B,NKV,HD,S)  ends 113.2MB
  // late-phase aliases (producers of aliased regions complete first)
  u16* oP   = (u16*)(ws + 37748736);     // 33.55MB f16 partials (aliases qkvh)
  float2* mlp = (float2*)(ws + 71303168);// 0.52MB (right after oP)
  u16* aout = (u16*)(ws + 0);            // 16.78MB f16 (aliases hs_f, gemm1 done)

  cvt_all_kernel<<<18432, 256, 0, stream>>>(hs, Wq, Wk, Wv, Wo, hs_f, w_f, wo_f);

  gemm256<8, 3, 1><<<dim3(16, 16), 512, 0, stream>>>(hs_f, w_f, qkvh, 4096, 3072, 2048);
  norm_rope_kernel<<<12288, 256, 0, stream>>>(qkvh, cosb, sinb, qw, kw, q_t, k_t, v_t);
  attn_kernel<<<dim3(16, 16), 512, 0, stream>>>(q_t, k_t, v_t, oP, mlp);
  combine_kernel<<<8192, 256, 0, stream>>>(oP, mlp, aout);
  gemm256<4, 4, 0><<<dim3(32, 8), 512, 0, stream>>>(aout, wo_f, out, 4096, 2048, 2048);
}